// Round 5
// baseline (69.657 us; speedup 1.0000x reference)
//
#include <hip/hip_runtime.h>
#include <stdint.h>

#define S_GRID 7
#define N_CH 30
#define MAXB 8192          // max compacted boxes (actual data: 6272)
#define NTILE (MAXB/256)   // 32 j-tiles
#define GATHER_WAVES (NTILE*4)

// ---- ws layout (bytes) ----
// 0      : float acc[4] {xy+wh, obj, nobj, class}
// 16     : int ctr          (compacted obj-cell counter)
// 20     : int finalCtr
// 4096   : float4 BP[MAXB]   (131072) -> 135168
// 135168 : float4 BT[MAXB]   (131072) -> 266240
// 266240 : float  ConfP[MAXB] (32768) -> 299008
// 299008 : float  AreaP[MAXB] (32768) -> 331776
// 331776 : u64 pkeys[nchunk][MAXB]  (nchunk*64 KiB)

__global__ void k_init(float* __restrict__ acc, int* __restrict__ ctr, int* __restrict__ finalCtr) {
    if (threadIdx.x < 4) acc[threadIdx.x] = 0.0f;
    if (threadIdx.x == 4) *ctr = 0;
    if (threadIdx.x == 5) *finalCtr = 0;
}

// one pass over P,T: unordered compaction (wave-aggregated atomic alloc) + cheap masked losses.
// Box order differs from the reference; the loss is order-invariant except for exact-bitwise
// IoU argmax ties (worst case ~0.003 on a 44.5 loss; threshold 0.89).
__global__ void k_prep(const float* __restrict__ P, const float* __restrict__ T, int ncell,
                       int* __restrict__ ctr,
                       float4* __restrict__ BP, float4* __restrict__ BT,
                       float* __restrict__ ConfP, float* __restrict__ AreaP,
                       float* __restrict__ acc) {
    int cell = blockIdx.x * 256 + threadIdx.x;
    const float* p = P + (size_t)cell * N_CH;
    const float* t = T + (size_t)cell * N_CH;
    int obj = 0;
    if (cell < ncell) obj = (t[4] == 1.0f);

    int lane = threadIdx.x & 63;
    unsigned long long b = __ballot(obj);
    int wcnt = __popcll(b);
    int base = 0;
    if (lane == 0 && wcnt) base = atomicAdd(ctr, wcnt);
    base = __shfl(base, 0);

    float cls = 0.f, nobj = 0.f;
    if (cell < ncell) {
        if (obj) {
            #pragma unroll
            for (int k = 10; k < 30; k++) { float d = p[k] - t[k]; cls += d * d; }
        } else {
            float d0 = p[4] - t[4], d1 = p[9] - t[9];
            nobj = d0 * d0 + d1 * d1;
        }
    }
    #pragma unroll
    for (int o = 32; o; o >>= 1) { cls += __shfl_down(cls, o); nobj += __shfl_down(nobj, o); }
    if (lane == 0) {
        if (cls != 0.f)  atomicAdd(&acc[3], cls);
        if (nobj != 0.f) atomicAdd(&acc[2], nobj);
    }

    if (obj) {
        int rank = base + __popcll(b & ((1ull << lane) - 1ull));
        #pragma unroll
        for (int bb = 0; bb < 2; ++bb) {
            int m = 2 * rank + bb;
            if (m < MAXB) {
                int o5 = bb * 5;
                float cx = p[o5 + 0] / (float)S_GRID, cy = p[o5 + 1] / (float)S_GRID;
                float w = p[o5 + 2], h = p[o5 + 3];
                float4 bp = make_float4(cx - 0.5f * w, cy - 0.5f * h, cx + 0.5f * w, cy + 0.5f * h);
                BP[m] = bp;
                AreaP[m] = (bp.z - bp.x) * (bp.w - bp.y);
                ConfP[m] = p[4 + o5];
                cx = t[o5 + 0] / (float)S_GRID; cy = t[o5 + 1] / (float)S_GRID;
                w = t[o5 + 2]; h = t[o5 + 3];
                BT[m] = make_float4(cx - 0.5f * w, cy - 0.5f * h, cx + 0.5f * w, cy + 0.5f * h);
            }
        }
    }
}

__global__ void k_match(const float4* __restrict__ BP, const float4* __restrict__ BT,
                        const float* __restrict__ AreaP,
                        const int* __restrict__ ctr,
                        unsigned long long* __restrict__ pkeys, int nchunk) {
    int nb = 2 * (*ctr); if (nb > MAXB) nb = MAXB;
    int j = blockIdx.x * 256 + threadIdx.x;
    int c = blockIdx.y;
    int chunkLen = (nb + nchunk - 1) / nchunk;
    int i0 = c * chunkLen;
    int i1 = min(nb, i0 + chunkLen);
    if (j >= nb || i0 >= i1) return;
    float4 tb = BT[j];
    float a2 = (tb.z - tb.x) * (tb.w - tb.y);
    // divide-free argmax: iou_i > iou_best  <=>  inter_i*bestD > bestN*u_i   (all >= 0, u > 0)
    float bestN = -1.f, bestD = 1.f;
    int bidx = 0;
    #pragma unroll 2
    for (int i = i0; i < i1; ++i) {
        float4 pb = BP[i];             // wave-uniform -> scalar (SMEM) loads
        float a1 = AreaP[i];
        float lx = fmaxf(pb.x, tb.x), ly = fmaxf(pb.y, tb.y);
        float rx = fminf(pb.z, tb.z), ry = fminf(pb.w, tb.w);
        float wx = fmaxf(rx - lx, 0.f), wy = fmaxf(ry - ly, 0.f);
        float inter = wx * wy;
        float u = (a1 + a2) - inter;
        if (__builtin_expect(inter * bestD > bestN * u, 0)) {  // strict: first occurrence wins
            bestN = inter; bestD = u; bidx = i;
        }
    }
    float best = bestN / bestD;        // one precise divide per (j,chunk)
    pkeys[(size_t)c * MAXB + j] =
        ((unsigned long long)__float_as_uint(best) << 32) |
        (unsigned long long)(0xFFFFFFFFu - (unsigned)bidx);
}

// gather + final combine fused; cross-block ordering via release/acquire atomics only
// (NO __threadfence: that cost ~170us across blocks in R3 -- per-block L2 writeback on 8 XCDs)
__global__ void k_gather(const float4* __restrict__ BP, const float4* __restrict__ BT,
                         const float* __restrict__ ConfP,
                         const int* __restrict__ ctr,
                         const unsigned long long* __restrict__ pkeys, int nchunk,
                         float* __restrict__ acc, int* __restrict__ finalCtr,
                         float* __restrict__ out, float inv_batch) {
    int nb = 2 * (*ctr); if (nb > MAXB) nb = MAXB;
    int j = blockIdx.x * 256 + threadIdx.x;
    float sxywh = 0.f, sobj = 0.f;
    if (j < nb) {
        int chunkLen = (nb + nchunk - 1) / nchunk;
        unsigned long long key = 0;
        for (int c = 0; c < nchunk; ++c) {
            if (c * chunkLen >= nb) break;
            unsigned long long k2 = pkeys[(size_t)c * MAXB + j];
            if (k2 > key) key = k2;      // bigger iou wins; ties -> smaller idx
        }
        float iou = __uint_as_float((unsigned)(key >> 32));
        unsigned idx = 0xFFFFFFFFu - (unsigned)(key & 0xFFFFFFFFull);
        float4 bp = BP[idx], bt = BT[idx];
        float cp = ConfP[idx];
        float dx = bp.x - bt.x, dy = bp.y - bt.y;
        float dw = sqrtf(bp.z) - sqrtf(bt.z);
        float dh = sqrtf(bp.w) - sqrtf(bt.w);
        sxywh = dx * dx + dy * dy + dw * dw + dh * dh;
        float dob = cp - iou;
        sobj = dob * dob;
    }
    #pragma unroll
    for (int o = 32; o; o >>= 1) { sxywh += __shfl_down(sxywh, o); sobj += __shfl_down(sobj, o); }

    if ((threadIdx.x & 63) == 0) {
        if (sxywh != 0.f) atomicAdd(&acc[0], sxywh);
        if (sobj != 0.f)  atomicAdd(&acc[1], sobj);
        // release-bump: orders this wave-leader's acc atomics before the counter increment
        int old = __hip_atomic_fetch_add(finalCtr, 1, __ATOMIC_ACQ_REL, __HIP_MEMORY_SCOPE_AGENT);
        if (old == GATHER_WAVES - 1) {   // last wave: all 128 leaders' adds are visible
            float a0 = __hip_atomic_load(&acc[0], __ATOMIC_RELAXED, __HIP_MEMORY_SCOPE_AGENT);
            float a1 = __hip_atomic_load(&acc[1], __ATOMIC_RELAXED, __HIP_MEMORY_SCOPE_AGENT);
            float a2 = __hip_atomic_load(&acc[2], __ATOMIC_RELAXED, __HIP_MEMORY_SCOPE_AGENT);
            float a3 = __hip_atomic_load(&acc[3], __ATOMIC_RELAXED, __HIP_MEMORY_SCOPE_AGENT);
            out[0] = (5.0f * a0 + 0.5f * a2 + a1 + a3) * inv_batch;
        }
    }
}

extern "C" void kernel_launch(void* const* d_in, const int* in_sizes, int n_in,
                              void* d_out, int out_size, void* d_ws, size_t ws_size,
                              hipStream_t stream) {
    const float* P = (const float*)d_in[0];
    const float* T = (const float*)d_in[1];
    int ncell = in_sizes[0] / N_CH;                 // 25088
    int batch = ncell / (S_GRID * S_GRID);          // 512

    char* ws = (char*)d_ws;
    float* acc      = (float*)ws;
    int*   ctr      = (int*)(ws + 16);
    int*   finalCtr = (int*)(ws + 20);
    float4* BP    = (float4*)(ws + 4096);
    float4* BT    = (float4*)(ws + 135168);
    float*  ConfP = (float*)(ws + 266240);
    float*  AreaP = (float*)(ws + 299008);
    const size_t pkeys_off = 331776;
    unsigned long long* pkeys = (unsigned long long*)(ws + pkeys_off);

    int nchunk = 64;
    while (nchunk > 8 && pkeys_off + (size_t)nchunk * MAXB * 8 > ws_size) nchunk >>= 1;

    int nblk = (ncell + 255) / 256;                 // 98
    k_init  <<<1, 64, 0, stream>>>(acc, ctr, finalCtr);
    k_prep  <<<nblk, 256, 0, stream>>>(P, T, ncell, ctr, BP, BT, ConfP, AreaP, acc);
    dim3 g3(NTILE, nchunk);
    k_match <<<g3, 256, 0, stream>>>(BP, BT, AreaP, ctr, pkeys, nchunk);
    k_gather<<<NTILE, 256, 0, stream>>>(BP, BT, ConfP, ctr, pkeys, nchunk, acc, finalCtr,
                                        (float*)d_out, 1.0f / (float)batch);
}

// Round 6
// 65.885 us; speedup vs baseline: 1.0573x; 1.0573x over previous
//
#include <hip/hip_runtime.h>
#include <stdint.h>

#define S_GRID 7
#define N_CH 30
#define MAXB 8192          // max compacted boxes (actual data: 6272)
#define NTILE (MAXB/256)   // 32 j-tiles
#define NCHUNK 64          // i-chunks

// ---- ws layout (bytes) ----
// 0      : float acc[4] {xy+wh, obj, nobj, class}
// 16     : int finalCtr
// 20     : int hdr       (nb = 2*ncoord)
// 64     : float pcls[128]   (per-block class partials)
// 576    : float pnobj[128]  (per-block noobj partials)
// 4096   : float4 BP[MAXB]   (131072) -> 135168
// 135168 : float4 BT[MAXB]   (131072) -> 266240
// 266240 : float  ConfP[MAXB] (32768) -> 299008
// 299008 : float  AreaP[MAXB] (32768) -> 331776
// 331776 : u64 pkeys[NCHUNK][MAXB]  (4 MiB)

// ONE pass over P,T, no pre-zeroed state needed:
//  - box rank via redundant prefix (re-count obj flags of earlier cells; L2-resident)
//    -> exact reference ordering, no atomic allocator, no init dispatch
//  - class/noobj -> per-block partial arrays (plain stores)
//  - block 0 zeroes acc/finalCtr for k_gather (visible at dispatch boundary)
//  - last block writes hdr = nb
__global__ void k_prep(const float* __restrict__ P, const float* __restrict__ T, int ncell,
                       float4* __restrict__ BP, float4* __restrict__ BT,
                       float* __restrict__ ConfP, float* __restrict__ AreaP,
                       float* __restrict__ pcls, float* __restrict__ pnobj,
                       float* __restrict__ acc, int* __restrict__ finalCtr,
                       int* __restrict__ hdr) {
    int b = blockIdx.x, tid = threadIdx.x;
    int lane = tid & 63, wid = tid >> 6;
    int cell = b * 256 + tid;
    const float* p = P + (size_t)cell * N_CH;
    const float* t = T + (size_t)cell * N_CH;
    bool obj = (cell < ncell) && (t[4] == 1.0f);

    if (b == 0) {
        if (tid < 4)  acc[tid] = 0.0f;
        if (tid == 4) *finalCtr = 0;
    }

    // exclusive prefix of obj count over cells [0, b*256), recomputed redundantly
    int pre = 0;
    int limit = b * 256;
    for (int c = tid; c < limit; c += 256)
        pre += (T[(size_t)c * N_CH + 4] == 1.0f) ? 1 : 0;
    #pragma unroll
    for (int o = 32; o; o >>= 1) pre += __shfl_down(pre, o);

    unsigned long long bm = __ballot(obj);

    // cheap masked losses, per-block partials
    float cls = 0.f, nob = 0.f;
    if (cell < ncell) {
        if (obj) {
            #pragma unroll
            for (int k = 10; k < 30; k++) { float d = p[k] - t[k]; cls += d * d; }
        } else {
            float d0 = p[4] - t[4], d1 = p[9] - t[9];
            nob = d0 * d0 + d1 * d1;
        }
    }
    #pragma unroll
    for (int o = 32; o; o >>= 1) { cls += __shfl_down(cls, o); nob += __shfl_down(nob, o); }

    __shared__ int   shPre[4], shCnt[4], shOfs[4];
    __shared__ float shC[4], shN[4];
    if (lane == 0) {
        shPre[wid] = pre; shCnt[wid] = __popcll(bm);
        shC[wid] = cls;   shN[wid] = nob;
    }
    __syncthreads();
    if (tid == 0) {
        int base = shPre[0] + shPre[1] + shPre[2] + shPre[3];
        int s = 0;
        #pragma unroll
        for (int w = 0; w < 4; w++) { shOfs[w] = base + s; s += shCnt[w]; }
        pcls[b]  = shC[0] + shC[1] + shC[2] + shC[3];
        pnobj[b] = shN[0] + shN[1] + shN[2] + shN[3];
        if (b == gridDim.x - 1) hdr[0] = 2 * (base + s);   // nb
    }
    __syncthreads();

    if (obj) {
        int rank = shOfs[wid] + __popcll(bm & ((1ull << lane) - 1ull));
        #pragma unroll
        for (int bb = 0; bb < 2; ++bb) {
            int m = 2 * rank + bb;
            if (m < MAXB) {
                int o5 = bb * 5;
                float cx = p[o5 + 0] / (float)S_GRID, cy = p[o5 + 1] / (float)S_GRID;
                float w = p[o5 + 2], h = p[o5 + 3];
                float4 bp = make_float4(cx - 0.5f * w, cy - 0.5f * h, cx + 0.5f * w, cy + 0.5f * h);
                BP[m] = bp;
                AreaP[m] = (bp.z - bp.x) * (bp.w - bp.y);
                ConfP[m] = p[4 + o5];
                cx = t[o5 + 0] / (float)S_GRID; cy = t[o5 + 1] / (float)S_GRID;
                w = t[o5 + 2]; h = t[o5 + 3];
                BT[m] = make_float4(cx - 0.5f * w, cy - 0.5f * h, cx + 0.5f * w, cy + 0.5f * h);
            }
        }
    }
}

__global__ void k_match(const float4* __restrict__ BP, const float4* __restrict__ BT,
                        const float* __restrict__ AreaP,
                        const int* __restrict__ hdr,
                        unsigned long long* __restrict__ pkeys) {
    int nb = hdr[0]; if (nb > MAXB) nb = MAXB;
    int j = blockIdx.x * 256 + threadIdx.x;
    int c = blockIdx.y;
    int chunkLen = (nb + NCHUNK - 1) / NCHUNK;
    int i0 = c * chunkLen;
    int i1 = min(nb, i0 + chunkLen);
    if (j >= nb || i0 >= i1) return;
    float4 tb = BT[j];
    float a2 = (tb.z - tb.x) * (tb.w - tb.y);
    // divide-free argmax: iou_i > iou_best  <=>  inter_i*bestD > bestN*u_i   (all >= 0, u > 0)
    float bestN = -1.f, bestD = 1.f;
    int bidx = 0;
    #pragma unroll 2
    for (int i = i0; i < i1; ++i) {
        float4 pb = BP[i];             // wave-uniform address
        float a1 = AreaP[i];
        float lx = fmaxf(pb.x, tb.x), ly = fmaxf(pb.y, tb.y);
        float rx = fminf(pb.z, tb.z), ry = fminf(pb.w, tb.w);
        float wx = fmaxf(rx - lx, 0.f), wy = fmaxf(ry - ly, 0.f);
        float inter = wx * wy;
        float u = (a1 + a2) - inter;
        if (__builtin_expect(inter * bestD > bestN * u, 0)) {  // strict: first occurrence wins
            bestN = inter; bestD = u; bidx = i;
        }
    }
    float best = bestN / bestD;        // one precise divide per (j,chunk)
    pkeys[(size_t)c * MAXB + j] =
        ((unsigned long long)__float_as_uint(best) << 32) |
        (unsigned long long)(0xFFFFFFFFu - (unsigned)bidx);
}

// gather + partial-array summation + final combine; cross-block ordering via atomics only
// (no __threadfence -- R3 showed per-block fences cost ~170us on 8 non-coherent L2s)
__global__ void k_gather(const float4* __restrict__ BP, const float4* __restrict__ BT,
                         const float* __restrict__ ConfP,
                         const int* __restrict__ hdr,
                         const unsigned long long* __restrict__ pkeys,
                         const float* __restrict__ pcls, const float* __restrict__ pnobj, int nblk,
                         float* __restrict__ acc, int* __restrict__ finalCtr,
                         float* __restrict__ out, float inv_batch) {
    int nb = hdr[0]; if (nb > MAXB) nb = MAXB;
    int tid = threadIdx.x;
    int j = blockIdx.x * 256 + tid;
    float sxywh = 0.f, sobj = 0.f;
    if (j < nb) {
        unsigned long long key = 0;
        #pragma unroll 4
        for (int c = 0; c < NCHUNK; ++c) {
            unsigned long long k2 = pkeys[(size_t)c * MAXB + j];
            if (k2 > key) key = k2;      // bigger iou wins; ties -> smaller idx
        }
        float iou = __uint_as_float((unsigned)(key >> 32));
        unsigned idx = 0xFFFFFFFFu - (unsigned)(key & 0xFFFFFFFFull);
        float4 bp = BP[idx], bt = BT[idx];
        float cp = ConfP[idx];
        float dx = bp.x - bt.x, dy = bp.y - bt.y;
        float dw = sqrtf(bp.z) - sqrtf(bt.z);
        float dh = sqrtf(bp.w) - sqrtf(bt.w);
        sxywh = dx * dx + dy * dy + dw * dw + dh * dh;
        float dob = cp - iou;
        sobj = dob * dob;
    }
    // block 0 also folds in the per-block class/noobj partials
    float exC = 0.f, exN = 0.f;
    if (blockIdx.x == 0 && tid < nblk) { exC = pcls[tid]; exN = pnobj[tid]; }

    #pragma unroll
    for (int o = 32; o; o >>= 1) {
        sxywh += __shfl_down(sxywh, o); sobj += __shfl_down(sobj, o);
        exC   += __shfl_down(exC, o);   exN  += __shfl_down(exN, o);
    }
    if ((tid & 63) == 0) {
        if (sxywh != 0.f) atomicAdd(&acc[0], sxywh);
        if (sobj != 0.f)  atomicAdd(&acc[1], sobj);
        if (exN != 0.f)   atomicAdd(&acc[2], exN);
        if (exC != 0.f)   atomicAdd(&acc[3], exC);
    }
    __syncthreads();                     // drains the wave-leader atomics (waitcnt before barrier)
    if (tid == 0) {
        int old = __hip_atomic_fetch_add(finalCtr, 1, __ATOMIC_ACQ_REL, __HIP_MEMORY_SCOPE_AGENT);
        if (old == NTILE - 1) {          // last block: all 32 blocks' adds visible
            float a0 = __hip_atomic_load(&acc[0], __ATOMIC_RELAXED, __HIP_MEMORY_SCOPE_AGENT);
            float a1 = __hip_atomic_load(&acc[1], __ATOMIC_RELAXED, __HIP_MEMORY_SCOPE_AGENT);
            float a2 = __hip_atomic_load(&acc[2], __ATOMIC_RELAXED, __HIP_MEMORY_SCOPE_AGENT);
            float a3 = __hip_atomic_load(&acc[3], __ATOMIC_RELAXED, __HIP_MEMORY_SCOPE_AGENT);
            out[0] = (5.0f * a0 + 0.5f * a2 + a1 + a3) * inv_batch;
        }
    }
}

extern "C" void kernel_launch(void* const* d_in, const int* in_sizes, int n_in,
                              void* d_out, int out_size, void* d_ws, size_t ws_size,
                              hipStream_t stream) {
    const float* P = (const float*)d_in[0];
    const float* T = (const float*)d_in[1];
    int ncell = in_sizes[0] / N_CH;                 // 25088
    int batch = ncell / (S_GRID * S_GRID);          // 512

    char* ws = (char*)d_ws;
    float* acc      = (float*)ws;
    int*   finalCtr = (int*)(ws + 16);
    int*   hdr      = (int*)(ws + 20);
    float* pcls     = (float*)(ws + 64);
    float* pnobj    = (float*)(ws + 576);
    float4* BP    = (float4*)(ws + 4096);
    float4* BT    = (float4*)(ws + 135168);
    float*  ConfP = (float*)(ws + 266240);
    float*  AreaP = (float*)(ws + 299008);
    unsigned long long* pkeys = (unsigned long long*)(ws + 331776);

    int nblk = (ncell + 255) / 256;                 // 98 (<=128 for pcls/pnobj)
    k_prep  <<<nblk, 256, 0, stream>>>(P, T, ncell, BP, BT, ConfP, AreaP,
                                       pcls, pnobj, acc, finalCtr, hdr);
    dim3 g3(NTILE, NCHUNK);
    k_match <<<g3, 256, 0, stream>>>(BP, BT, AreaP, hdr, pkeys);
    k_gather<<<NTILE, 256, 0, stream>>>(BP, BT, ConfP, hdr, pkeys, pcls, pnobj, nblk,
                                        acc, finalCtr, (float*)d_out, 1.0f / (float)batch);
}